// Round 3
// baseline (1462.641 us; speedup 1.0000x reference)
//
#include <hip/hip_runtime.h>

#define HIDDEN  64
#define T_STEPS 2048
#define N_INPUT 5
#define DT      0.1f
#define LN_EPS  1e-5f
#define ROWS    16                     // batch rows per block (MFMA N)
#define TANH_K  2.885390081777927f     // 2*log2(e)

typedef short bf16x8 __attribute__((ext_vector_type(8)));
typedef float f32x4  __attribute__((ext_vector_type(4)));

union FragU { uint4 u4; unsigned int u[4]; unsigned short us[8]; bf16x8 v; };

__device__ __forceinline__ unsigned short bf16_trunc(float f) {
    return (unsigned short)(__float_as_uint(f) >> 16);
}
__device__ __forceinline__ float bf16_hi_f32(float f) {
    return __uint_as_float(__float_as_uint(f) & 0xFFFF0000u);
}
// [lo16 = f0.hi16 | hi16 = f1.hi16] in ONE v_perm_b32
__device__ __forceinline__ unsigned int pack_hi2(float f0, float f1) {
    return __builtin_amdgcn_perm(__float_as_uint(f1), __float_as_uint(f0), 0x07060302u);
}
// workgroup barrier WITHOUT the vmcnt(0) drain __syncthreads() would emit:
// LDS ordering (lgkmcnt) is all the cross-wave exchanges need; global x-prefetch
// loads stay in flight across the barrier.
__device__ __forceinline__ void lds_barrier() {
    asm volatile("s_waitcnt lgkmcnt(0)\n\ts_barrier" ::: "memory");
}

#define MFMA(A, B, C) __builtin_amdgcn_mfma_f32_16x16x32_bf16((A), (B), (C), 0, 0, 0)

__global__ __launch_bounds__(256, 1) void hlnn_mfma5(
    const float* __restrict__ x, const float* __restrict__ W_in,
    const float* __restrict__ b_in, const float* __restrict__ tau_param,
    const float* __restrict__ W_rec, const float* __restrict__ ln1_w,
    const float* __restrict__ ln1_b, const float* __restrict__ ln2_w,
    const float* __restrict__ ln2_b, const float* __restrict__ head_W,
    const float* __restrict__ head_b, float* __restrict__ out, int Btot)
{
    const int tid  = threadIdx.x;
    const int lane = tid & 63;
    const int w    = tid >> 6;        // wave id = hidden 16-col tile
    const int r    = lane & 15;       // batch row within group
    const int q    = lane >> 4;       // quad
    const int g    = blockIdx.x;      // 16-row group

    // h transposed transport: [row][hidden] bf16, 72-ushort (144B) row stride
    __shared__ unsigned short hHi[ROWS][72];
    __shared__ unsigned short hLo[ROWS][72];
    __shared__ float2 stats2[ROWS][18];        // [row][4w+q] raw partials (+2 pad)
    __shared__ float  hnbuf[ROWS][68];         // epilogue LN2 output

    // ---- static A fragments: A[m=r][k=q*8+j] = W_rec[k][16w+m], split hi/lo
    FragU A_hi[2], A_lo[2];
    const int cfrag = 16 * w + r;
#pragma unroll
    for (int kk = 0; kk < 2; ++kk)
#pragma unroll
        for (int j = 0; j < 8; ++j) {
            const float wv = W_rec[(kk * 32 + q * 8 + j) * HIDDEN + cfrag];
            A_hi[kk].us[j] = bf16_trunc(wv);
            A_lo[kk].us[j] = bf16_trunc(wv - bf16_hi_f32(wv));
        }
    FragU Ax_hi, Ax_lo;                        // W_in^T, K=32 (rows >=5 zero)
#pragma unroll
    for (int j = 0; j < 8; ++j) {
        const int kg = q * 8 + j;
        const float wv = (kg < N_INPUT) ? W_in[kg * HIDDEN + cfrag] : 0.0f;
        Ax_hi.us[j] = bf16_trunc(wv);
        Ax_lo.us[j] = bf16_trunc(wv - bf16_hi_f32(wv));
    }

    // ---- per-lane elementwise constants: lane owns (c = 16w+4q+e, row r)
    float w1K[4], b1K[4], dec4[4], ln2w4[4], ln2b4[4];
    f32x4 cinit;
#pragma unroll
    for (int e = 0; e < 4; ++e) {
        const int c = 16 * w + 4 * q + e;
        w1K[e]  = ln1_w[c] * TANH_K;
        b1K[e]  = ln1_b[c] * TANH_K;
        const float tp  = tau_param[c];
        const float tau = (tp > 20.0f) ? tp : log1pf(expf(tp));   // softplus
        dec4[e]  = 1.0f - DT / tau;
        ln2w4[e] = ln2_w[c];  ln2b4[e] = ln2_b[c];
        cinit[e] = b_in[c];
    }

    const float* xrow = x + (size_t)(g * ROWS + r) * T_STEPS * N_INPUT;

    // ---- prime the h transport buffers to h(-1) = 0
    for (int i = tid; i < ROWS * 36; i += 256) {
        ((unsigned int*)hHi)[i] = 0u;
        ((unsigned int*)hLo)[i] = 0u;
    }

    // ---- preheader: accx(0) from x(0); xc = x(1) (prefetch distance 2 in-loop)
    const f32x4 zero4 = {0.f, 0.f, 0.f, 0.f};
    f32x4 accx;
    {
        const float x0 = xrow[0], x1 = xrow[1], x2 = xrow[2], x3 = xrow[3], x4 = xrow[4];
        FragU BxH, BxL;
        BxH.u[0] = pack_hi2(x0, x1); BxH.u[1] = pack_hi2(x2, x3);
        BxH.u[2] = pack_hi2(x4, 0.f); BxH.u[3] = 0u;
        BxL.u[0] = pack_hi2(x0 - bf16_hi_f32(x0), x1 - bf16_hi_f32(x1));
        BxL.u[1] = pack_hi2(x2 - bf16_hi_f32(x2), x3 - bf16_hi_f32(x3));
        BxL.u[2] = pack_hi2(x4 - bf16_hi_f32(x4), 0.f); BxL.u[3] = 0u;
        accx = MFMA(Ax_hi.v, BxH.v, cinit);
        accx = MFMA(Ax_hi.v, BxL.v, accx);
        accx = MFMA(Ax_lo.v, BxH.v, accx);
    }
    float xc0 = xrow[N_INPUT + 0], xc1 = xrow[N_INPUT + 1], xc2 = xrow[N_INPUT + 2],
          xc3 = xrow[N_INPUT + 3], xc4 = xrow[N_INPUT + 4];

    float h[4] = {0.f, 0.f, 0.f, 0.f};
    __syncthreads();   // priming visible (preheader only; full drain is fine here)

    for (int t = 0; t < T_STEPS; ++t) {
        // 1. global prefetch x(t+2) — no barrier will drain these anymore
        const size_t toff = (size_t)((t + 2 < T_STEPS) ? (t + 2) : (T_STEPS - 1)) * N_INPUT;
        const float xf0 = xrow[toff + 0], xf1 = xrow[toff + 1], xf2 = xrow[toff + 2],
                    xf3 = xrow[toff + 3], xf4 = xrow[toff + 4];

        // 2. B-frags for this step (h(t-1); primed zeros at t=0)
        FragU Bh0, Bl0, Bh1, Bl1;
        Bh0.u4 = *(const uint4*)&hHi[r][q * 8];
        Bl0.u4 = *(const uint4*)&hLo[r][q * 8];
        Bh1.u4 = *(const uint4*)&hHi[r][32 + q * 8];
        Bl1.u4 = *(const uint4*)&hLo[r][32 + q * 8];

        // 3. x-side MFMAs for t+1 from xc — no LDS dep, fills the Bh-read shadow
        f32x4 accx_n;
        {
            FragU BxH, BxL;
            BxH.u[0] = pack_hi2(xc0, xc1); BxH.u[1] = pack_hi2(xc2, xc3);
            BxH.u[2] = pack_hi2(xc4, 0.f); BxH.u[3] = 0u;
            BxL.u[0] = pack_hi2(xc0 - bf16_hi_f32(xc0), xc1 - bf16_hi_f32(xc1));
            BxL.u[1] = pack_hi2(xc2 - bf16_hi_f32(xc2), xc3 - bf16_hi_f32(xc3));
            BxL.u[2] = pack_hi2(xc4 - bf16_hi_f32(xc4), 0.f); BxL.u[3] = 0u;
            accx_n = MFMA(Ax_hi.v, BxH.v, cinit);
            accx_n = MFMA(Ax_hi.v, BxL.v, accx_n);
            accx_n = MFMA(Ax_lo.v, BxH.v, accx_n);
        }

        // 4. h-side MFMAs: three independent 2-deep chains + pair adds
        f32x4 c0 = MFMA(A_hi[0].v, Bh0.v, accx);
        f32x4 c1 = MFMA(A_hi[1].v, Bh1.v, zero4);
        f32x4 c2 = MFMA(A_lo[0].v, Bh0.v, zero4);
        c0 = MFMA(A_hi[0].v, Bl0.v, c0);
        c1 = MFMA(A_hi[1].v, Bl1.v, c1);
        c2 = MFMA(A_lo[1].v, Bh1.v, c2);
        const f32x4 acc = (c0 + c1) + c2;

        // 5. raw per-lane stats partial -> LDS
        const float p1 = (acc[0] + acc[1]) + (acc[2] + acc[3]);
        const float p2 = fmaf(acc[0], acc[0], fmaf(acc[1], acc[1],
                         fmaf(acc[2], acc[2], acc[3] * acc[3])));
        stats2[r][4 * w + q] = make_float2(p1, p2);
        lds_barrier();                                     // B1 (no vmcnt drain)

        // row reduce: 16 partials, 8x b128 (4 q-lanes share addr -> broadcast)
        const float4* sp = (const float4*)&stats2[r][0];
        const float4 v0 = sp[0], v1 = sp[1], v2 = sp[2], v3 = sp[3];
        const float4 v4 = sp[4], v5 = sp[5], v6 = sp[6], v7 = sp[7];
        const float sum = (((v0.x + v0.z) + (v1.x + v1.z)) + ((v2.x + v2.z) + (v3.x + v3.z)))
                        + (((v4.x + v4.z) + (v5.x + v5.z)) + ((v6.x + v6.z) + (v7.x + v7.z)));
        const float ssq = (((v0.y + v0.w) + (v1.y + v1.w)) + ((v2.y + v2.w) + (v3.y + v3.w)))
                        + (((v4.y + v4.w) + (v5.y + v5.w)) + ((v6.y + v6.w) + (v7.y + v7.w)));

        const float mu   = sum * (1.0f / 64.0f);
        float var        = fmaf(mu, -mu, ssq * (1.0f / 64.0f));
        var              = fmaxf(var, 0.0f);
        const float rstd = __builtin_amdgcn_rsqf(var + LN_EPS);

        // 6. f = tanh(LN(pre)); h = clip(decay*h + dt*f)
#pragma unroll
        for (int e = 0; e < 4; ++e) {
            const float a1c = rstd * w1K[e];
            const float tt  = fmaf(acc[e], a1c, fmaf(-mu, a1c, b1K[e]));
            const float ex  = __builtin_amdgcn_exp2f(tt);
            const float rc  = __builtin_amdgcn_rcpf(ex + 1.0f);
            const float dtf = fmaf(DT, ex, -DT) * rc;      // DT * tanh
            const float hv  = fmaf(dec4[e], h[e], dtf);
            h[e] = fminf(fmaxf(hv, -10.0f), 10.0f);
        }

        // 7. split h -> bf16 hi/lo, write transposed to LDS
        const int c0w = 16 * w + 4 * q;
        {
            const float l0 = h[0] - bf16_hi_f32(h[0]), l1v = h[1] - bf16_hi_f32(h[1]);
            const float l2 = h[2] - bf16_hi_f32(h[2]), l3v = h[3] - bf16_hi_f32(h[3]);
            *(uint2*)&hHi[r][c0w] = make_uint2(pack_hi2(h[0], h[1]), pack_hi2(h[2], h[3]));
            *(uint2*)&hLo[r][c0w] = make_uint2(pack_hi2(l0, l1v),   pack_hi2(l2, l3v));
        }
        lds_barrier();                                     // B2 (no vmcnt drain)

        // 8. rotate prefetch state
        accx = accx_n;
        xc0 = xf0; xc1 = xf1; xc2 = xf2; xc3 = xf3; xc4 = xf4;
    }

    // ---- epilogue: LN2 on final h (loop ended at B2: stats2 safe to reuse) ----
    {
        const float p1 = (h[0] + h[1]) + (h[2] + h[3]);
        const float p2 = fmaf(h[0], h[0], fmaf(h[1], h[1], fmaf(h[2], h[2], h[3] * h[3])));
        stats2[r][4 * w + q] = make_float2(p1, p2);
        __syncthreads();
        const float4* sp = (const float4*)&stats2[r][0];
        const float4 v0 = sp[0], v1 = sp[1], v2 = sp[2], v3 = sp[3];
        const float4 v4 = sp[4], v5 = sp[5], v6 = sp[6], v7 = sp[7];
        const float sum = (((v0.x + v0.z) + (v1.x + v1.z)) + ((v2.x + v2.z) + (v3.x + v3.z)))
                        + (((v4.x + v4.z) + (v5.x + v5.z)) + ((v6.x + v6.z) + (v7.x + v7.z)));
        const float ssq = (((v0.y + v0.w) + (v1.y + v1.w)) + ((v2.y + v2.w) + (v3.y + v3.w)))
                        + (((v4.y + v4.w) + (v5.y + v5.w)) + ((v6.y + v6.w) + (v7.y + v7.w)));
        const float mu   = sum * (1.0f / 64.0f);
        float var        = fmaf(mu, -mu, ssq * (1.0f / 64.0f));
        var              = fmaxf(var, 0.0f);
        const float rstd = __builtin_amdgcn_rsqf(var + LN_EPS);
        const int c0w = 16 * w + 4 * q;
        float4 hn;
        hn.x = fmaf((h[0] - mu) * rstd, ln2w4[0], ln2b4[0]);
        hn.y = fmaf((h[1] - mu) * rstd, ln2w4[1], ln2b4[1]);
        hn.z = fmaf((h[2] - mu) * rstd, ln2w4[2], ln2b4[2]);
        hn.w = fmaf((h[3] - mu) * rstd, ln2w4[3], ln2b4[3]);
        *(float4*)&hnbuf[r][c0w] = hn;
    }
    __syncthreads();

    for (int o = tid; o < ROWS * 20; o += 256) {
        const int rr = o / 20, ka = o % 20;
        float p = head_b[ka];
#pragma unroll
        for (int c = 0; c < HIDDEN; ++c)
            p = fmaf(hnbuf[rr][c], head_W[ka * HIDDEN + c], p);
        const int k = ka >> 2, a = ka & 3;     // out[k][b][a], shape (5,B,4)
        out[(size_t)k * Btot * 4 + (size_t)(g * ROWS + rr) * 4 + a] = p;
    }
}

extern "C" void kernel_launch(void* const* d_in, const int* in_sizes, int n_in,
                              void* d_out, int out_size, void* d_ws, size_t ws_size,
                              hipStream_t stream) {
    const float* x         = (const float*)d_in[0];
    const float* W_in      = (const float*)d_in[1];
    const float* b_in      = (const float*)d_in[2];
    const float* tau_param = (const float*)d_in[3];
    const float* W_rec     = (const float*)d_in[4];
    const float* ln1_w     = (const float*)d_in[5];
    const float* ln1_b     = (const float*)d_in[6];
    const float* ln2_w     = (const float*)d_in[7];
    const float* ln2_b     = (const float*)d_in[8];
    const float* head_W    = (const float*)d_in[9];
    const float* head_b    = (const float*)d_in[10];

    const int B = in_sizes[0] / (T_STEPS * N_INPUT);   // 4096
    dim3 grid(B / ROWS), block(256);                   // 256 blocks x 4 waves
    hipLaunchKernelGGL(hlnn_mfma5, grid, block, 0, stream,
                       x, W_in, b_in, tau_param, W_rec, ln1_w, ln1_b,
                       ln2_w, ln2_b, head_W, head_b, (float*)d_out, B);
}

// Round 4
// 1328.543 us; speedup vs baseline: 1.1009x; 1.1009x over previous
//
#include <hip/hip_runtime.h>

#define HIDDEN  64
#define T_STEPS 2048
#define N_INPUT 5
#define DT      0.1f
#define LN_EPS  1e-5f
#define ROWS    16                     // batch rows per block (MFMA N)
#define TANH_K  2.885390081777927f     // 2*log2(e)

typedef short bf16x8 __attribute__((ext_vector_type(8)));
typedef float f32x4  __attribute__((ext_vector_type(4)));

union FragU { uint4 u4; unsigned int u[4]; unsigned short us[8]; bf16x8 v; };

__device__ __forceinline__ unsigned short bf16_trunc(float f) {
    return (unsigned short)(__float_as_uint(f) >> 16);
}
__device__ __forceinline__ float bf16_hi_f32(float f) {
    return __uint_as_float(__float_as_uint(f) & 0xFFFF0000u);
}
// [lo16 = f0.hi16 | hi16 = f1.hi16] in ONE v_perm_b32
__device__ __forceinline__ unsigned int pack_hi2(float f0, float f1) {
    return __builtin_amdgcn_perm(__float_as_uint(f1), __float_as_uint(f0), 0x07060302u);
}
// workgroup barrier WITHOUT the vmcnt(0) drain __syncthreads() would emit.
__device__ __forceinline__ void lds_barrier() {
    asm volatile("s_waitcnt lgkmcnt(0)\n\ts_barrier" ::: "memory");
}

#define MFMA(A, B, C) __builtin_amdgcn_mfma_f32_16x16x32_bf16((A), (B), (C), 0, 0, 0)

// Round-2 skeleton (best: 1242us): 4 waves, wave w owns hidden cols [16w,16w+16).
// Per step: h-MFMAs FIRST (3 chains x 2-deep), stats raw-partial exchange (B1),
// x-side MFMA for t+1 in the stats-read latency shadow, tanh, h exchange (B2).
// x-pack VALU sits at loop top to fill the exposed Bh lgkm-wait.
__global__ __launch_bounds__(256, 1) void hlnn_mfma6(
    const float* __restrict__ x, const float* __restrict__ W_in,
    const float* __restrict__ b_in, const float* __restrict__ tau_param,
    const float* __restrict__ W_rec, const float* __restrict__ ln1_w,
    const float* __restrict__ ln1_b, const float* __restrict__ ln2_w,
    const float* __restrict__ ln2_b, const float* __restrict__ head_W,
    const float* __restrict__ head_b, float* __restrict__ out, int Btot)
{
    const int tid  = threadIdx.x;
    const int lane = tid & 63;
    const int w    = tid >> 6;        // wave id = hidden 16-col tile
    const int r    = lane & 15;       // batch row within group
    const int q    = lane >> 4;       // quad
    const int g    = blockIdx.x;      // 16-row group

    // h transposed transport: [row][hidden] bf16, 72-ushort (144B) row stride
    __shared__ unsigned short hHi[ROWS][72];
    __shared__ unsigned short hLo[ROWS][72];
    __shared__ float2 stats2[ROWS][18];        // [row][4w+q] raw partials (+2 pad)
    __shared__ float  hnbuf[ROWS][68];         // epilogue LN2 output

    // ---- static A fragments: A[m=r][k=q*8+j] = W_rec[k][16w+m], split hi/lo
    FragU A_hi[2], A_lo[2];
    const int cfrag = 16 * w + r;
#pragma unroll
    for (int kk = 0; kk < 2; ++kk)
#pragma unroll
        for (int j = 0; j < 8; ++j) {
            const float wv = W_rec[(kk * 32 + q * 8 + j) * HIDDEN + cfrag];
            A_hi[kk].us[j] = bf16_trunc(wv);
            A_lo[kk].us[j] = bf16_trunc(wv - bf16_hi_f32(wv));
        }
    FragU Ax_hi, Ax_lo;                        // W_in^T, K=32 (rows >=5 zero)
#pragma unroll
    for (int j = 0; j < 8; ++j) {
        const int kg = q * 8 + j;
        const float wv = (kg < N_INPUT) ? W_in[kg * HIDDEN + cfrag] : 0.0f;
        Ax_hi.us[j] = bf16_trunc(wv);
        Ax_lo.us[j] = bf16_trunc(wv - bf16_hi_f32(wv));
    }

    // ---- per-lane elementwise constants: lane owns (c = 16w+4q+e, row r)
    float w1K[4], b1K[4], dec4[4], ln2w4[4], ln2b4[4];
    f32x4 cinit;
#pragma unroll
    for (int e = 0; e < 4; ++e) {
        const int c = 16 * w + 4 * q + e;
        w1K[e]  = ln1_w[c] * TANH_K;
        b1K[e]  = ln1_b[c] * TANH_K;
        const float tp  = tau_param[c];
        const float tau = (tp > 20.0f) ? tp : log1pf(expf(tp));   // softplus
        dec4[e]  = 1.0f - DT / tau;
        ln2w4[e] = ln2_w[c];  ln2b4[e] = ln2_b[c];
        cinit[e] = b_in[c];
    }

    const float* xrow = x + (size_t)(g * ROWS + r) * T_STEPS * N_INPUT;

    // ---- preheader: accx(0) from x(0); xc = x(1); in-loop prefetch = x(t+2)
    const f32x4 zero4 = {0.f, 0.f, 0.f, 0.f};
    f32x4 accx;
    {
        const float x0 = xrow[0], x1 = xrow[1], x2 = xrow[2], x3 = xrow[3], x4 = xrow[4];
        FragU BxH, BxL;
        BxH.u[0] = pack_hi2(x0, x1); BxH.u[1] = pack_hi2(x2, x3);
        BxH.u[2] = pack_hi2(x4, 0.f); BxH.u[3] = 0u;
        BxL.u[0] = pack_hi2(x0 - bf16_hi_f32(x0), x1 - bf16_hi_f32(x1));
        BxL.u[1] = pack_hi2(x2 - bf16_hi_f32(x2), x3 - bf16_hi_f32(x3));
        BxL.u[2] = pack_hi2(x4 - bf16_hi_f32(x4), 0.f); BxL.u[3] = 0u;
        accx = MFMA(Ax_hi.v, BxH.v, cinit);
        accx = MFMA(Ax_hi.v, BxL.v, accx);
        accx = MFMA(Ax_lo.v, BxH.v, accx);
    }
    float xc0 = xrow[N_INPUT + 0], xc1 = xrow[N_INPUT + 1], xc2 = xrow[N_INPUT + 2],
          xc3 = xrow[N_INPUT + 3], xc4 = xrow[N_INPUT + 4];

    FragU Bh0, Bl0, Bh1, Bl1;                  // h^T B-frags (h0 = 0)
    Bh0.u4 = make_uint4(0,0,0,0); Bl0.u4 = make_uint4(0,0,0,0);
    Bh1.u4 = make_uint4(0,0,0,0); Bl1.u4 = make_uint4(0,0,0,0);
    float h[4] = {0.f, 0.f, 0.f, 0.f};

    int tof = 2 * N_INPUT;                     // uniform offset of x(t+2); scalar-pipe math

#pragma unroll 2
    for (int t = 0; t < T_STEPS; ++t) {
        // 1. issue global prefetch x(t+2): uniform offset -> SALU bump + clamp
        const float xf0 = xrow[tof + 0], xf1 = xrow[tof + 1], xf2 = xrow[tof + 2],
                    xf3 = xrow[tof + 3], xf4 = xrow[tof + 4];
        tof = min(tof + N_INPUT, (T_STEPS - 1) * N_INPUT);

        // 2. x-pack for x(t+1) (VALU only): fills the Bh lgkm-wait, no MFMA here
        FragU BxH, BxL;
        BxH.u[0] = pack_hi2(xc0, xc1); BxH.u[1] = pack_hi2(xc2, xc3);
        BxH.u[2] = pack_hi2(xc4, 0.f); BxH.u[3] = 0u;
        BxL.u[0] = pack_hi2(xc0 - bf16_hi_f32(xc0), xc1 - bf16_hi_f32(xc1));
        BxL.u[1] = pack_hi2(xc2 - bf16_hi_f32(xc2), xc3 - bf16_hi_f32(xc3));
        BxL.u[2] = pack_hi2(xc4 - bf16_hi_f32(xc4), 0.f); BxL.u[3] = 0u;

        // 3. h-side MFMAs: three independent 2-deep chains + pair adds
        f32x4 c0 = MFMA(A_hi[0].v, Bh0.v, accx);
        f32x4 c1 = MFMA(A_hi[1].v, Bh1.v, zero4);
        f32x4 c2 = MFMA(A_lo[0].v, Bh0.v, zero4);
        c0 = MFMA(A_hi[0].v, Bl0.v, c0);
        c1 = MFMA(A_hi[1].v, Bl1.v, c1);
        c2 = MFMA(A_lo[1].v, Bh1.v, c2);
        const f32x4 acc = (c0 + c1) + c2;

        // 4. raw per-lane stats partial -> LDS (balanced trees)
        const float p1 = (acc[0] + acc[1]) + (acc[2] + acc[3]);
        const float p2 = fmaf(acc[1], acc[1], acc[0] * acc[0])
                       + fmaf(acc[3], acc[3], acc[2] * acc[2]);
        stats2[r][4 * w + q] = make_float2(p1, p2);
        lds_barrier();                                     // B1

        // 5. row reduce: 16 partials, 8x b128 (4 q-lanes share addr -> broadcast)
        const float4* sp = (const float4*)&stats2[r][0];
        const float4 v0 = sp[0], v1 = sp[1], v2 = sp[2], v3 = sp[3];
        const float4 v4 = sp[4], v5 = sp[5], v6 = sp[6], v7 = sp[7];
        const float sum = (((v0.x + v0.z) + (v1.x + v1.z)) + ((v2.x + v2.z) + (v3.x + v3.z)))
                        + (((v4.x + v4.z) + (v5.x + v5.z)) + ((v6.x + v6.z) + (v7.x + v7.z)));
        const float ssq = (((v0.y + v0.w) + (v1.y + v1.w)) + ((v2.y + v2.w) + (v3.y + v3.w)))
                        + (((v4.y + v4.w) + (v5.y + v5.w)) + ((v6.y + v6.w) + (v7.y + v7.w)));

        // 6. x-side MFMAs for t+1: in the stats-read latency shadow (round-2 spot)
        f32x4 accx_n = MFMA(Ax_hi.v, BxH.v, cinit);
        accx_n = MFMA(Ax_hi.v, BxL.v, accx_n);
        accx_n = MFMA(Ax_lo.v, BxH.v, accx_n);

        const float mu   = sum * (1.0f / 64.0f);
        float var        = fmaf(mu, -mu, ssq * (1.0f / 64.0f));
        var              = fmaxf(var, 0.0f);
        const float rstd = __builtin_amdgcn_rsqf(var + LN_EPS);

        // 7. f = tanh(LN(pre)); h = clamp(decay*h + dt*f)
#pragma unroll
        for (int e = 0; e < 4; ++e) {
            const float a1c = rstd * w1K[e];
            const float tt  = fmaf(acc[e], a1c, fmaf(-mu, a1c, b1K[e]));
            const float ex  = __builtin_amdgcn_exp2f(tt);
            const float rc  = __builtin_amdgcn_rcpf(ex + 1.0f);
            const float dtf = fmaf(DT, ex, -DT) * rc;      // DT * tanh
            const float hv  = fmaf(dec4[e], h[e], dtf);
            h[e] = __builtin_amdgcn_fmed3f(hv, -10.0f, 10.0f);
        }

        // 8. split h -> bf16 hi/lo, write transposed to LDS
        const int c0w = 16 * w + 4 * q;
        {
            const float l0 = h[0] - bf16_hi_f32(h[0]), l1v = h[1] - bf16_hi_f32(h[1]);
            const float l2 = h[2] - bf16_hi_f32(h[2]), l3v = h[3] - bf16_hi_f32(h[3]);
            *(uint2*)&hHi[r][c0w] = make_uint2(pack_hi2(h[0], h[1]), pack_hi2(h[2], h[3]));
            *(uint2*)&hLo[r][c0w] = make_uint2(pack_hi2(l0, l1v),   pack_hi2(l2, l3v));
        }
        lds_barrier();                                     // B2

        // 9. B-frags for next step (max distance to use at next loop top)
        Bh0.u4 = *(const uint4*)&hHi[r][q * 8];
        Bl0.u4 = *(const uint4*)&hLo[r][q * 8];
        Bh1.u4 = *(const uint4*)&hHi[r][32 + q * 8];
        Bl1.u4 = *(const uint4*)&hLo[r][32 + q * 8];

        // 10. rotate prefetch state (renamed away by unroll-2)
        accx = accx_n;
        xc0 = xf0; xc1 = xf1; xc2 = xf2; xc3 = xf3; xc4 = xf4;
    }

    // ---- epilogue: LN2 on final h (loop ended at B2: stats2 safe to reuse) ----
    {
        const float p1 = (h[0] + h[1]) + (h[2] + h[3]);
        const float p2 = fmaf(h[1], h[1], h[0] * h[0])
                       + fmaf(h[3], h[3], h[2] * h[2]);
        stats2[r][4 * w + q] = make_float2(p1, p2);
        __syncthreads();
        const float4* sp = (const float4*)&stats2[r][0];
        const float4 v0 = sp[0], v1 = sp[1], v2 = sp[2], v3 = sp[3];
        const float4 v4 = sp[4], v5 = sp[5], v6 = sp[6], v7 = sp[7];
        const float sum = (((v0.x + v0.z) + (v1.x + v1.z)) + ((v2.x + v2.z) + (v3.x + v3.z)))
                        + (((v4.x + v4.z) + (v5.x + v5.z)) + ((v6.x + v6.z) + (v7.x + v7.z)));
        const float ssq = (((v0.y + v0.w) + (v1.y + v1.w)) + ((v2.y + v2.w) + (v3.y + v3.w)))
                        + (((v4.y + v4.w) + (v5.y + v5.w)) + ((v6.y + v6.w) + (v7.y + v7.w)));
        const float mu   = sum * (1.0f / 64.0f);
        float var        = fmaf(mu, -mu, ssq * (1.0f / 64.0f));
        var              = fmaxf(var, 0.0f);
        const float rstd = __builtin_amdgcn_rsqf(var + LN_EPS);
        const int c0w = 16 * w + 4 * q;
        float4 hn;
        hn.x = fmaf((h[0] - mu) * rstd, ln2w4[0], ln2b4[0]);
        hn.y = fmaf((h[1] - mu) * rstd, ln2w4[1], ln2b4[1]);
        hn.z = fmaf((h[2] - mu) * rstd, ln2w4[2], ln2b4[2]);
        hn.w = fmaf((h[3] - mu) * rstd, ln2w4[3], ln2b4[3]);
        *(float4*)&hnbuf[r][c0w] = hn;
    }
    __syncthreads();

    for (int o = tid; o < ROWS * 20; o += 256) {
        const int rr = o / 20, ka = o % 20;
        float p = head_b[ka];
#pragma unroll
        for (int c = 0; c < HIDDEN; ++c)
            p = fmaf(hnbuf[rr][c], head_W[ka * HIDDEN + c], p);
        const int k = ka >> 2, a = ka & 3;     // out[k][b][a], shape (5,B,4)
        out[(size_t)k * Btot * 4 + (size_t)(g * ROWS + rr) * 4 + a] = p;
    }
}

extern "C" void kernel_launch(void* const* d_in, const int* in_sizes, int n_in,
                              void* d_out, int out_size, void* d_ws, size_t ws_size,
                              hipStream_t stream) {
    const float* x         = (const float*)d_in[0];
    const float* W_in      = (const float*)d_in[1];
    const float* b_in      = (const float*)d_in[2];
    const float* tau_param = (const float*)d_in[3];
    const float* W_rec     = (const float*)d_in[4];
    const float* ln1_w     = (const float*)d_in[5];
    const float* ln1_b     = (const float*)d_in[6];
    const float* ln2_w     = (const float*)d_in[7];
    const float* ln2_b     = (const float*)d_in[8];
    const float* head_W    = (const float*)d_in[9];
    const float* head_b    = (const float*)d_in[10];

    const int B = in_sizes[0] / (T_STEPS * N_INPUT);   // 4096
    dim3 grid(B / ROWS), block(256);                   // 256 blocks x 4 waves
    hipLaunchKernelGGL(hlnn_mfma6, grid, block, 0, stream,
                       x, W_in, b_in, tau_param, W_rec, ln1_w, ln1_b,
                       ln2_w, ln2_b, head_W, head_b, (float*)d_out, B);
}